// Round 11
// baseline (138.209 us; speedup 1.0000x reference)
//
#include <hip/hip_runtime.h>
#include <hip/hip_bf16.h>

// B=8192 rows, N=64 nodes, C=256. Per node: MLP 1->C->C->1 on s=Q*Y, then
// softmax over [z0, z_1..z_64]. Output f32 [B, 65].
//
// Round 11: piecewise-linear rewrite (all-f32), R10 bugfixes:
//  (1) branchless exact lower_bound (R10's fixed-8 bisection corrupted lo),
//  (2) eval sums ALL 128 d-pairs (R10 read only q<64 -> half of d missing).
// h1_k(s) = relu(w1_k s + b1_k) flips at knee s*_k = -b1_k/w1_k. So
// g_d(s) = alpha_d(I) s + beta_d(I) on each of 257 intervals of sorted knees.
// table[(n*257+I)*128+pr] = float4{a_d0, b_d0, a_d1, b_d1} via prefix scan.
// Per sample: interval search + 128x float4 (fma,max,fma): O(C) not O(C^2).

typedef unsigned int u32;

// ---------------------------------------------------------------------------
// Kernel 0: S[n][b] = Q[b][n]*Y[b][n]  (node-major, 64x64 LDS transpose)
// ---------------------------------------------------------------------------
__global__ __launch_bounds__(256) void make_s(
    const float* __restrict__ Q, const float* __restrict__ Y,
    float* __restrict__ S)
{
    __shared__ float ts[64][65];
    const int b0 = blockIdx.x << 6;
    #pragma unroll
    for (int jj = 0; jj < 16; jj++) {
        int idx = threadIdx.x + (jj << 8);
        int r = idx >> 6, c = idx & 63;
        ts[r][c] = Q[(size_t)(b0 + r) * 64 + c] * Y[(size_t)(b0 + r) * 64 + c];
    }
    __syncthreads();
    #pragma unroll
    for (int jj = 0; jj < 16; jj++) {
        int idx = threadIdx.x + (jj << 8);
        int nn = idx >> 6, bb = idx & 63;
        S[((size_t)nn << 13) + b0 + bb] = ts[bb][nn];
    }
}

// ---------------------------------------------------------------------------
// Kernel 1: per node, knees s*_k = -b1_k/w1_k, bitonic sort (key + index).
// ---------------------------------------------------------------------------
__global__ __launch_bounds__(256) void knee_sort(
    const float* __restrict__ W1, const float* __restrict__ b1,
    float* __restrict__ knots, int* __restrict__ perm)
{
    __shared__ float key[256];
    __shared__ int   idx[256];
    const int n = blockIdx.x;
    const int t = threadIdx.x;
    {
        float w = W1[n * 256 + t];
        float b = b1[n * 256 + t];
        key[t] = -b / w;                 // +-inf when w ~ 0: sorts to the ends
        idx[t] = t;
    }
    __syncthreads();
    for (int k = 2; k <= 256; k <<= 1) {
        for (int j = k >> 1; j > 0; j >>= 1) {
            int p = t ^ j;
            if (p > t) {
                float a = key[t], c = key[p];
                bool up = ((t & k) == 0);
                if (up ? (a > c) : (a < c)) {
                    int ia = idx[t];
                    key[t] = c; idx[t] = idx[p];
                    key[p] = a; idx[p] = ia;
                }
            }
            __syncthreads();
        }
    }
    knots[n * 256 + t] = key[t];
    perm[n * 256 + t]  = idx[t];
}

// ---------------------------------------------------------------------------
// Kernel 2: prefix-scan build of the interval table (f32).
// Interval 0: active set = {k : w1_k < 0}. Crossing sorted knee j (k=perm[j]):
// alpha += W2[k,:]*|w1_k|; beta += W2[k,:]*(w1_k>0 ? b1_k : -b1_k).
// grid (64 nodes, 2 d-halves) x 64 threads; thread owns a d-pair.
// ---------------------------------------------------------------------------
__global__ __launch_bounds__(64) void scan_build(
    const float* __restrict__ W1, const float* __restrict__ b1,
    const float* __restrict__ W2, const float* __restrict__ b2,
    const int* __restrict__ perm, float4* __restrict__ table)
{
    __shared__ float w1s[256], b1s[256];
    __shared__ int   pm[256];
    const int n  = blockIdx.x;
    const int pr = (blockIdx.y << 6) + threadIdx.x;   // pair 0..127
    const int d0 = pr << 1;
    for (int i = threadIdx.x; i < 256; i += 64) {
        w1s[i] = W1[n * 256 + i];
        b1s[i] = b1[n * 256 + i];
        pm[i]  = perm[n * 256 + i];
    }
    __syncthreads();

    const float* W2n = W2 + ((size_t)n << 16);

    float a0 = 0.f, c0 = 0.f, a1 = 0.f, c1 = 0.f;
    for (int k = 0; k < 256; ++k) {
        float w = w1s[k];
        if (w < 0.f) {                       // wave-uniform branch
            float2 v = *reinterpret_cast<const float2*>(&W2n[k * 256 + d0]);
            a0 = fmaf(v.x, w, a0); c0 = fmaf(v.x, b1s[k], c0);
            a1 = fmaf(v.y, w, a1); c1 = fmaf(v.y, b1s[k], c1);
        }
    }
    c0 += b2[n * 256 + d0];
    c1 += b2[n * 256 + d0 + 1];

    float4* trow = table + (size_t)n * 257 * 128 + pr;
    trow[0] = make_float4(a0, c0, a1, c1);
    #pragma unroll 8
    for (int j = 0; j < 256; ++j) {
        int   kj  = pm[j];
        float w   = w1s[kj];
        float bb  = b1s[kj];
        float cs  = (w > 0.f) ? bb : -bb;
        float awk = fabsf(w);
        float2 v = *reinterpret_cast<const float2*>(&W2n[kj * 256 + d0]);
        a0 = fmaf(v.x, awk, a0); c0 = fmaf(v.x, cs, c0);
        a1 = fmaf(v.y, awk, a1); c1 = fmaf(v.y, cs, c1);
        trow[(size_t)(j + 1) * 128] = make_float4(a0, c0, a1, c1);
    }
}

// ---------------------------------------------------------------------------
// Kernel 3: evaluate z[n][b]. Block = (node, 1024-sample chunk), 256 thr.
// Branchless lower_bound, count-sort samples by interval (LDS) so lanes share
// table rows, then 128 x float4 x 4 samples with fma/max/fma + w3 from LDS.
// ---------------------------------------------------------------------------
__global__ __launch_bounds__(256) void eval_nodes(
    const float* __restrict__ S, const float* __restrict__ knots,
    const float4* __restrict__ table, const float* __restrict__ W3,
    const float* __restrict__ b3, float* __restrict__ Z)
{
    __shared__ float kn[256];
    __shared__ float w3s[256];
    __shared__ float ssv[1024];
    __shared__ u32   meta[1024];
    __shared__ u32   hist[257];

    const int n   = blockIdx.x;
    const int c0  = blockIdx.y << 10;
    const int tid = threadIdx.x;
    const int lane = tid & 63;

    kn[tid]  = knots[n * 256 + tid];
    w3s[tid] = W3[n * 256 + tid];
    hist[tid] = 0;
    if (tid == 0) hist[256] = 0;

    const float* Sn = S + ((size_t)n << 13) + c0;
    float sv[4]; int iv[4];
    #pragma unroll
    for (int j = 0; j < 4; ++j) sv[j] = Sn[tid + (j << 8)];
    __syncthreads();

    #pragma unroll
    for (int j = 0; j < 4; ++j) {
        float s = sv[j];
        // branchless lower_bound: I = #knots < s, in [0,256]
        int I = 0;
        #pragma unroll
        for (int step = 128; step >= 1; step >>= 1)
            if (kn[I + step - 1] < s) I += step;
        if (kn[I > 255 ? 255 : I] < s && I < 256) I += 1;
        // note: after the 8 steps I <= 255; the final check promotes to 256
        iv[j] = I;
        atomicAdd(&hist[I], 1u);
    }
    __syncthreads();

    // wave-parallel exclusive prefix over hist[0..255]
    if (tid < 64) {
        int base = tid << 2;
        u32 h0 = hist[base], h1 = hist[base + 1], h2 = hist[base + 2], h3 = hist[base + 3];
        u32 lsum = h0 + h1 + h2 + h3;
        u32 run = lsum;
        #pragma unroll
        for (int off = 1; off < 64; off <<= 1) {
            u32 tt = __shfl_up(run, off, 64);
            if (lane >= off) run += tt;
        }
        u32 excl = run - lsum;
        hist[base]     = excl;
        hist[base + 1] = excl + h0;
        hist[base + 2] = excl + h0 + h1;
        hist[base + 3] = excl + h0 + h1 + h2;
        if (tid == 63) hist[256] = excl + lsum;
    }
    __syncthreads();

    #pragma unroll
    for (int j = 0; j < 4; ++j) {
        u32 pos = atomicAdd(&hist[iv[j]], 1u);
        ssv[pos]  = sv[j];
        meta[pos] = ((u32)iv[j] << 10) | (u32)(tid + (j << 8));
    }
    __syncthreads();

    const float b3n = b3[n];
    const float4* tb = table + (size_t)n * 257 * 128;

    float sj[4]; int bl[4]; const float4* rp[4];
    #pragma unroll
    for (int j = 0; j < 4; ++j) {
        int p = tid + (j << 8);
        sj[j] = ssv[p];
        u32 m = meta[p];
        bl[j] = (int)(m & 1023u);
        rp[j] = tb + (size_t)(m >> 10) * 128;
    }
    float acc[4] = {0.f, 0.f, 0.f, 0.f};
    #pragma unroll 2
    for (int q = 0; q < 128; ++q) {          // ALL 128 d-pairs (R10 bug: 64)
        float2 w3q = *reinterpret_cast<const float2*>(&w3s[q << 1]);
        #pragma unroll
        for (int j = 0; j < 4; ++j) {
            float4 v = rp[j][q];
            float h0 = fmaxf(fmaf(v.x, sj[j], v.y), 0.f);
            float h1 = fmaxf(fmaf(v.z, sj[j], v.w), 0.f);
            acc[j] = fmaf(h0, w3q.x, fmaf(h1, w3q.y, acc[j]));
        }
    }
    #pragma unroll
    for (int j = 0; j < 4; ++j)
        Z[((size_t)n << 13) + c0 + bl[j]] = acc[j] + b3n;
}

// ---------------------------------------------------------------------------
// Kernel 4: per-row 65-way softmax. One wave per batch row (lane = node).
// Z node-major: Z[n][b].
// ---------------------------------------------------------------------------
__global__ __launch_bounds__(256) void softmax_rows(
    const float* __restrict__ Q, const float* __restrict__ Y,
    const float* __restrict__ Z, const float* __restrict__ bias0,
    float* __restrict__ out)
{
    const int lane = threadIdx.x & 63;
    const int wv   = threadIdx.x >> 6;
    const int b    = (blockIdx.x << 2) + wv;

    float s = Q[(size_t)b * 64 + lane] * Y[(size_t)b * 64 + lane];
    float ssum = s;
    #pragma unroll
    for (int mask = 32; mask >= 1; mask >>= 1) ssum += __shfl_xor(ssum, mask, 64);
    const float z0 = bias0[0] - ssum;

    float zl = Z[((size_t)lane << 13) + b];
    float mx = zl;
    #pragma unroll
    for (int mask = 32; mask >= 1; mask >>= 1) mx = fmaxf(mx, __shfl_xor(mx, mask, 64));
    mx = fmaxf(mx, z0);

    float el = expf(zl - mx);
    float e0 = expf(z0 - mx);
    float den = el;
    #pragma unroll
    for (int mask = 32; mask >= 1; mask >>= 1) den += __shfl_xor(den, mask, 64);
    den += e0;
    const float inv = 1.0f / den;

    out[(size_t)b * 65 + 1 + lane] = el * inv;
    if (lane == 0) out[(size_t)b * 65] = e0 * inv;
}

// ---------------------------------------------------------------------------
extern "C" void kernel_launch(void* const* d_in, const int* in_sizes, int n_in,
                              void* d_out, int out_size, void* d_ws, size_t ws_size,
                              hipStream_t stream)
{
    const float* Q     = (const float*)d_in[0];
    const float* Y     = (const float*)d_in[1];
    const float* W1    = (const float*)d_in[2];
    const float* b1    = (const float*)d_in[3];
    const float* W2    = (const float*)d_in[4];
    const float* b2    = (const float*)d_in[5];
    const float* W3    = (const float*)d_in[6];
    const float* b3    = (const float*)d_in[7];
    const float* bias0 = (const float*)d_in[8];
    float* out = (float*)d_out;

    // ws layout (bytes):
    // [0        ) table  64*257*128*16 = 33,685,504
    // [33685504 ) S      2,097,152
    // [35782656 ) Z      2,097,152
    // [37879808 ) knots  65,536
    // [37945344 ) perm   65,536      total 38,010,880
    char* ws = (char*)d_ws;
    float4* table = (float4*)ws;
    float* S     = (float*)(ws + 33685504);
    float* Z     = (float*)(ws + 35782656);
    float* knots = (float*)(ws + 37879808);
    int*   perm  = (int*)  (ws + 37945344);

    make_s<<<128, 256, 0, stream>>>(Q, Y, S);
    knee_sort<<<64, 256, 0, stream>>>(W1, b1, knots, perm);
    scan_build<<<dim3(64, 2), 64, 0, stream>>>(W1, b1, W2, b2, perm, table);
    eval_nodes<<<dim3(64, 8), 256, 0, stream>>>(S, knots, table, W3, b3, Z);
    softmax_rows<<<2048, 256, 0, stream>>>(Q, Y, Z, bias0, out);
}

// Round 12
// 83.101 us; speedup vs baseline: 1.6631x; 1.6631x over previous
//
#include <hip/hip_runtime.h>
#include <hip/hip_bf16.h>

// B=8192 rows, N=64 nodes, C=256. Per node: MLP 1->C->C->1 on s=Q*Y, then
// softmax over [z0, z_1..z_64]. Output f32 [B, 65].
//
// Round 12: piecewise-linear rewrite; scan_build parallelized 32x.
// R11's scan_build: 128 waves total, serial 256-iter chain -> 95us, 1% occ.
// Now: 3-phase segmented scan, grid (64 nodes x 8 d-strips) x 256 thr
// (16 segs x 16 d-pairs): partial sums -> seg prefix -> re-walk & write.

typedef unsigned int u32;

// ---------------------------------------------------------------------------
// Kernel 0: S[n][b] = Q[b][n]*Y[b][n]  (node-major, 64x64 LDS transpose)
// ---------------------------------------------------------------------------
__global__ __launch_bounds__(256) void make_s(
    const float* __restrict__ Q, const float* __restrict__ Y,
    float* __restrict__ S)
{
    __shared__ float ts[64][65];
    const int b0 = blockIdx.x << 6;
    #pragma unroll
    for (int jj = 0; jj < 16; jj++) {
        int idx = threadIdx.x + (jj << 8);
        int r = idx >> 6, c = idx & 63;
        ts[r][c] = Q[(size_t)(b0 + r) * 64 + c] * Y[(size_t)(b0 + r) * 64 + c];
    }
    __syncthreads();
    #pragma unroll
    for (int jj = 0; jj < 16; jj++) {
        int idx = threadIdx.x + (jj << 8);
        int nn = idx >> 6, bb = idx & 63;
        S[((size_t)nn << 13) + b0 + bb] = ts[bb][nn];
    }
}

// ---------------------------------------------------------------------------
// Kernel 1: per node, knees s*_k = -b1_k/w1_k, bitonic sort (key + index).
// ---------------------------------------------------------------------------
__global__ __launch_bounds__(256) void knee_sort(
    const float* __restrict__ W1, const float* __restrict__ b1,
    float* __restrict__ knots, int* __restrict__ perm)
{
    __shared__ float key[256];
    __shared__ int   idx[256];
    const int n = blockIdx.x;
    const int t = threadIdx.x;
    {
        float w = W1[n * 256 + t];
        float b = b1[n * 256 + t];
        key[t] = -b / w;                 // +-inf when w ~ 0: sorts to the ends
        idx[t] = t;
    }
    __syncthreads();
    for (int k = 2; k <= 256; k <<= 1) {
        for (int j = k >> 1; j > 0; j >>= 1) {
            int p = t ^ j;
            if (p > t) {
                float a = key[t], c = key[p];
                bool up = ((t & k) == 0);
                if (up ? (a > c) : (a < c)) {
                    int ia = idx[t];
                    key[t] = c; idx[t] = idx[p];
                    key[p] = a; idx[p] = ia;
                }
            }
            __syncthreads();
        }
    }
    knots[n * 256 + t] = key[t];
    perm[n * 256 + t]  = idx[t];
}

// ---------------------------------------------------------------------------
// Kernel 2: segmented-scan build of the interval table (f32).
// table[(n*257+I)*128+pr] = float4{alpha_d0, beta_d0, alpha_d1, beta_d1}.
// Interval 0 (base): active = {k : w1_k < 0}: alpha += W2*w1, beta += W2*b1
// (+b2). Crossing sorted knee j (k=perm[j]): alpha += W2*|w1|,
// beta += W2*(w1>0 ? b1 : -b1).
// grid (64 nodes, 8 d-strips of 32), 256 thr = (seg 0..15) x (pair 0..15).
// ---------------------------------------------------------------------------
__global__ __launch_bounds__(256) void scan_build(
    const float* __restrict__ W1, const float* __restrict__ b1,
    const float* __restrict__ W2, const float* __restrict__ b2,
    const int* __restrict__ perm, float4* __restrict__ table)
{
    __shared__ float w1s[256], b1s[256];
    __shared__ int   pm[256];
    __shared__ float part[16][16][8];   // [seg][pr][ba0,bc0,ba1,bc1,da0,dc0,da1,dc1]

    const int n    = blockIdx.x;
    const int strip= blockIdx.y;          // d-strip of 32
    const int tid  = threadIdx.x;
    const int prl  = tid & 15;            // pair within strip
    const int seg  = tid >> 4;            // knee segment of 16
    const int prg  = (strip << 4) + prl;  // global pair 0..127
    const int d0   = prg << 1;

    if (tid < 256) {
        w1s[tid] = W1[n * 256 + tid];
        b1s[tid] = b1[n * 256 + tid];
        pm[tid]  = perm[n * 256 + tid];
    }
    __syncthreads();

    const float* W2n = W2 + ((size_t)n << 16);

    // ---- phase 1: per-segment partials ----
    {
        float ba0 = 0.f, bc0 = 0.f, ba1 = 0.f, bc1 = 0.f;  // base (w1<0) terms
        float da0 = 0.f, dc0 = 0.f, da1 = 0.f, dc1 = 0.f;  // crossing deltas
        #pragma unroll 4
        for (int i = 0; i < 16; ++i) {
            int   kj = pm[(seg << 4) + i];
            float w  = w1s[kj];
            float bb = b1s[kj];
            float2 v = *reinterpret_cast<const float2*>(&W2n[kj * 256 + d0]);
            if (w < 0.f) {
                ba0 = fmaf(v.x, w, ba0); bc0 = fmaf(v.x, bb, bc0);
                ba1 = fmaf(v.y, w, ba1); bc1 = fmaf(v.y, bb, bc1);
            }
            float aw = fabsf(w);
            float cs = (w > 0.f) ? bb : -bb;
            da0 = fmaf(v.x, aw, da0); dc0 = fmaf(v.x, cs, dc0);
            da1 = fmaf(v.y, aw, da1); dc1 = fmaf(v.y, cs, dc1);
        }
        float* p = part[seg][prl];
        p[0] = ba0; p[1] = bc0; p[2] = ba1; p[3] = bc1;
        p[4] = da0; p[5] = dc0; p[6] = da1; p[7] = dc1;
    }
    __syncthreads();

    // ---- phase 2: base totals + exclusive seg prefix (16 threads) ----
    if (tid < 16) {
        const int pr = tid;
        float sa0 = 0.f, sc0 = 0.f, sa1 = 0.f, sc1 = 0.f;
        #pragma unroll
        for (int sg = 0; sg < 16; ++sg) {
            const float* p = part[sg][pr];
            sa0 += p[0]; sc0 += p[1]; sa1 += p[2]; sc1 += p[3];
        }
        const int dd = ((strip << 4) + pr) << 1;
        sc0 += b2[n * 256 + dd];
        sc1 += b2[n * 256 + dd + 1];
        // table row 0 = base
        table[(size_t)n * 257 * 128 + ((strip << 4) + pr)] =
            make_float4(sa0, sc0, sa1, sc1);
        // start values per segment (overwrite part[sg][pr][0..3])
        float ra0 = sa0, rc0 = sc0, ra1 = sa1, rc1 = sc1;
        #pragma unroll
        for (int sg = 0; sg < 16; ++sg) {
            float* p = part[sg][pr];
            float t4 = p[4], t5 = p[5], t6 = p[6], t7 = p[7];
            p[0] = ra0; p[1] = rc0; p[2] = ra1; p[3] = rc1;
            ra0 += t4; rc0 += t5; ra1 += t6; rc1 += t7;
        }
    }
    __syncthreads();

    // ---- phase 3: re-walk segment from start, write 16 rows ----
    {
        const float* p = part[seg][prl];
        float a0 = p[0], c0 = p[1], a1 = p[2], c1 = p[3];
        float4* trow = table + (size_t)n * 257 * 128 + prg;
        #pragma unroll 4
        for (int i = 0; i < 16; ++i) {
            int   j  = (seg << 4) + i;
            int   kj = pm[j];
            float w  = w1s[kj];
            float bb = b1s[kj];
            float2 v = *reinterpret_cast<const float2*>(&W2n[kj * 256 + d0]);
            float aw = fabsf(w);
            float cs = (w > 0.f) ? bb : -bb;
            a0 = fmaf(v.x, aw, a0); c0 = fmaf(v.x, cs, c0);
            a1 = fmaf(v.y, aw, a1); c1 = fmaf(v.y, cs, c1);
            trow[(size_t)(j + 1) * 128] = make_float4(a0, c0, a1, c1);
        }
    }
}

// ---------------------------------------------------------------------------
// Kernel 3: evaluate z[n][b]. Block = (node, 1024-sample chunk), 256 thr.
// Branchless lower_bound, count-sort samples by interval (LDS) so lanes share
// table rows, then 128 x float4 x 4 samples with fma/max/fma + w3 from LDS.
// ---------------------------------------------------------------------------
__global__ __launch_bounds__(256) void eval_nodes(
    const float* __restrict__ S, const float* __restrict__ knots,
    const float4* __restrict__ table, const float* __restrict__ W3,
    const float* __restrict__ b3, float* __restrict__ Z)
{
    __shared__ float kn[256];
    __shared__ float w3s[256];
    __shared__ float ssv[1024];
    __shared__ u32   meta[1024];
    __shared__ u32   hist[257];

    const int n   = blockIdx.x;
    const int c0  = blockIdx.y << 10;
    const int tid = threadIdx.x;
    const int lane = tid & 63;

    kn[tid]  = knots[n * 256 + tid];
    w3s[tid] = W3[n * 256 + tid];
    hist[tid] = 0;
    if (tid == 0) hist[256] = 0;

    const float* Sn = S + ((size_t)n << 13) + c0;
    float sv[4]; int iv[4];
    #pragma unroll
    for (int j = 0; j < 4; ++j) sv[j] = Sn[tid + (j << 8)];
    __syncthreads();

    #pragma unroll
    for (int j = 0; j < 4; ++j) {
        float s = sv[j];
        // branchless lower_bound: I = #knots < s, in [0,256]
        int I = 0;
        #pragma unroll
        for (int step = 128; step >= 1; step >>= 1)
            if (kn[I + step - 1] < s) I += step;
        if (kn[I > 255 ? 255 : I] < s && I < 256) I += 1;
        iv[j] = I;
        atomicAdd(&hist[I], 1u);
    }
    __syncthreads();

    // wave-parallel exclusive prefix over hist[0..255]
    if (tid < 64) {
        int base = tid << 2;
        u32 h0 = hist[base], h1 = hist[base + 1], h2 = hist[base + 2], h3 = hist[base + 3];
        u32 lsum = h0 + h1 + h2 + h3;
        u32 run = lsum;
        #pragma unroll
        for (int off = 1; off < 64; off <<= 1) {
            u32 tt = __shfl_up(run, off, 64);
            if (lane >= off) run += tt;
        }
        u32 excl = run - lsum;
        hist[base]     = excl;
        hist[base + 1] = excl + h0;
        hist[base + 2] = excl + h0 + h1;
        hist[base + 3] = excl + h0 + h1 + h2;
        if (tid == 63) hist[256] = excl + lsum;
    }
    __syncthreads();

    #pragma unroll
    for (int j = 0; j < 4; ++j) {
        u32 pos = atomicAdd(&hist[iv[j]], 1u);
        ssv[pos]  = sv[j];
        meta[pos] = ((u32)iv[j] << 10) | (u32)(tid + (j << 8));
    }
    __syncthreads();

    const float b3n = b3[n];
    const float4* tb = table + (size_t)n * 257 * 128;

    float sj[4]; int bl[4]; const float4* rp[4];
    #pragma unroll
    for (int j = 0; j < 4; ++j) {
        int p = tid + (j << 8);
        sj[j] = ssv[p];
        u32 m = meta[p];
        bl[j] = (int)(m & 1023u);
        rp[j] = tb + (size_t)(m >> 10) * 128;
    }
    float acc[4] = {0.f, 0.f, 0.f, 0.f};
    #pragma unroll 2
    for (int q = 0; q < 128; ++q) {
        float2 w3q = *reinterpret_cast<const float2*>(&w3s[q << 1]);
        #pragma unroll
        for (int j = 0; j < 4; ++j) {
            float4 v = rp[j][q];
            float h0 = fmaxf(fmaf(v.x, sj[j], v.y), 0.f);
            float h1 = fmaxf(fmaf(v.z, sj[j], v.w), 0.f);
            acc[j] = fmaf(h0, w3q.x, fmaf(h1, w3q.y, acc[j]));
        }
    }
    #pragma unroll
    for (int j = 0; j < 4; ++j)
        Z[((size_t)n << 13) + c0 + bl[j]] = acc[j] + b3n;
}

// ---------------------------------------------------------------------------
// Kernel 4: per-row 65-way softmax. One wave per batch row (lane = node).
// Z node-major: Z[n][b].
// ---------------------------------------------------------------------------
__global__ __launch_bounds__(256) void softmax_rows(
    const float* __restrict__ Q, const float* __restrict__ Y,
    const float* __restrict__ Z, const float* __restrict__ bias0,
    float* __restrict__ out)
{
    const int lane = threadIdx.x & 63;
    const int wv   = threadIdx.x >> 6;
    const int b    = (blockIdx.x << 2) + wv;

    float s = Q[(size_t)b * 64 + lane] * Y[(size_t)b * 64 + lane];
    float ssum = s;
    #pragma unroll
    for (int mask = 32; mask >= 1; mask >>= 1) ssum += __shfl_xor(ssum, mask, 64);
    const float z0 = bias0[0] - ssum;

    float zl = Z[((size_t)lane << 13) + b];
    float mx = zl;
    #pragma unroll
    for (int mask = 32; mask >= 1; mask >>= 1) mx = fmaxf(mx, __shfl_xor(mx, mask, 64));
    mx = fmaxf(mx, z0);

    float el = expf(zl - mx);
    float e0 = expf(z0 - mx);
    float den = el;
    #pragma unroll
    for (int mask = 32; mask >= 1; mask >>= 1) den += __shfl_xor(den, mask, 64);
    den += e0;
    const float inv = 1.0f / den;

    out[(size_t)b * 65 + 1 + lane] = el * inv;
    if (lane == 0) out[(size_t)b * 65] = e0 * inv;
}

// ---------------------------------------------------------------------------
extern "C" void kernel_launch(void* const* d_in, const int* in_sizes, int n_in,
                              void* d_out, int out_size, void* d_ws, size_t ws_size,
                              hipStream_t stream)
{
    const float* Q     = (const float*)d_in[0];
    const float* Y     = (const float*)d_in[1];
    const float* W1    = (const float*)d_in[2];
    const float* b1    = (const float*)d_in[3];
    const float* W2    = (const float*)d_in[4];
    const float* b2    = (const float*)d_in[5];
    const float* W3    = (const float*)d_in[6];
    const float* b3    = (const float*)d_in[7];
    const float* bias0 = (const float*)d_in[8];
    float* out = (float*)d_out;

    // ws layout (bytes):
    // [0        ) table  64*257*128*16 = 33,685,504
    // [33685504 ) S      2,097,152
    // [35782656 ) Z      2,097,152
    // [37879808 ) knots  65,536
    // [37945344 ) perm   65,536      total 38,010,880
    char* ws = (char*)d_ws;
    float4* table = (float4*)ws;
    float* S     = (float*)(ws + 33685504);
    float* Z     = (float*)(ws + 35782656);
    float* knots = (float*)(ws + 37879808);
    int*   perm  = (int*)  (ws + 37945344);

    make_s<<<128, 256, 0, stream>>>(Q, Y, S);
    knee_sort<<<64, 256, 0, stream>>>(W1, b1, knots, perm);
    scan_build<<<dim3(64, 8), 256, 0, stream>>>(W1, b1, W2, b2, perm, table);
    eval_nodes<<<dim3(64, 8), 256, 0, stream>>>(S, knots, table, W3, b3, Z);
    softmax_rows<<<2048, 256, 0, stream>>>(Q, Y, Z, bias0, out);
}

// Round 13
// 81.013 us; speedup vs baseline: 1.7060x; 1.0258x over previous
//
#include <hip/hip_runtime.h>
#include <hip/hip_bf16.h>

// B=8192 rows, N=64 nodes, C=256. Per node: MLP 1->C->C->1 on s=Q*Y, then
// softmax over [z0, z_1..z_64]. Output f32 [B, 65].
//
// Round 13: piecewise-linear path, eval de-latencied.
//  - eval: 1 sample/thread, grid (64,32) -> 32 waves/CU (was 8); sorted
//    consecutive lanes share table rows (broadcast loads).
//  - table bf16-packed: entry u32 = (bf16 alpha | bf16 beta << 16); row 1KB.
//  - softmax reads Z via 64x64 LDS transpose (was 32KB-stride scatter).

typedef unsigned int u32;

__device__ __forceinline__ unsigned short f2bf(float f) {
    u32 u = __float_as_uint(f);
    u += 0x7FFFu + ((u >> 16) & 1u);   // RNE
    return (unsigned short)(u >> 16);
}
__device__ __forceinline__ u32 pk2(float a, float b) {   // lo=bf16(a), hi=bf16(b)
    return (u32)f2bf(a) | ((u32)f2bf(b) << 16);
}
__device__ __forceinline__ float bfl(u32 u) { return __uint_as_float(u << 16); }
__device__ __forceinline__ float bfh(u32 u) { return __uint_as_float(u & 0xFFFF0000u); }

// ---------------------------------------------------------------------------
// Kernel 0: S[n][b] = Q[b][n]*Y[b][n]  (node-major, 64x64 LDS transpose)
// ---------------------------------------------------------------------------
__global__ __launch_bounds__(256) void make_s(
    const float* __restrict__ Q, const float* __restrict__ Y,
    float* __restrict__ S)
{
    __shared__ float ts[64][65];
    const int b0 = blockIdx.x << 6;
    #pragma unroll
    for (int jj = 0; jj < 16; jj++) {
        int idx = threadIdx.x + (jj << 8);
        int r = idx >> 6, c = idx & 63;
        ts[r][c] = Q[(size_t)(b0 + r) * 64 + c] * Y[(size_t)(b0 + r) * 64 + c];
    }
    __syncthreads();
    #pragma unroll
    for (int jj = 0; jj < 16; jj++) {
        int idx = threadIdx.x + (jj << 8);
        int nn = idx >> 6, bb = idx & 63;
        S[((size_t)nn << 13) + b0 + bb] = ts[bb][nn];
    }
}

// ---------------------------------------------------------------------------
// Kernel 1: per node, knees s*_k = -b1_k/w1_k, bitonic sort (key + index).
// ---------------------------------------------------------------------------
__global__ __launch_bounds__(256) void knee_sort(
    const float* __restrict__ W1, const float* __restrict__ b1,
    float* __restrict__ knots, int* __restrict__ perm)
{
    __shared__ float key[256];
    __shared__ int   idx[256];
    const int n = blockIdx.x;
    const int t = threadIdx.x;
    {
        float w = W1[n * 256 + t];
        float b = b1[n * 256 + t];
        key[t] = -b / w;                 // +-inf when w ~ 0: sorts to the ends
        idx[t] = t;
    }
    __syncthreads();
    for (int k = 2; k <= 256; k <<= 1) {
        for (int j = k >> 1; j > 0; j >>= 1) {
            int p = t ^ j;
            if (p > t) {
                float a = key[t], c = key[p];
                bool up = ((t & k) == 0);
                if (up ? (a > c) : (a < c)) {
                    int ia = idx[t];
                    key[t] = c; idx[t] = idx[p];
                    key[p] = a; idx[p] = ia;
                }
            }
            __syncthreads();
        }
    }
    knots[n * 256 + t] = key[t];
    perm[n * 256 + t]  = idx[t];
}

// ---------------------------------------------------------------------------
// Kernel 2: segmented-scan build of the bf16-packed interval table.
// table[(n*257+I)*128+pr] = uint2{ pk2(alpha_d0,beta_d0), pk2(alpha_d1,beta_d1) }.
// grid (64 nodes, 8 d-strips of 32), 256 thr = (seg 0..15) x (pair 0..15).
// ---------------------------------------------------------------------------
__global__ __launch_bounds__(256) void scan_build(
    const float* __restrict__ W1, const float* __restrict__ b1,
    const float* __restrict__ W2, const float* __restrict__ b2,
    const int* __restrict__ perm, uint2* __restrict__ table)
{
    __shared__ float w1s[256], b1s[256];
    __shared__ int   pm[256];
    __shared__ float part[16][16][8];

    const int n    = blockIdx.x;
    const int strip= blockIdx.y;
    const int tid  = threadIdx.x;
    const int prl  = tid & 15;
    const int seg  = tid >> 4;
    const int prg  = (strip << 4) + prl;
    const int d0   = prg << 1;

    w1s[tid] = W1[n * 256 + tid];
    b1s[tid] = b1[n * 256 + tid];
    pm[tid]  = perm[n * 256 + tid];
    __syncthreads();

    const float* W2n = W2 + ((size_t)n << 16);

    // ---- phase 1: per-segment partials ----
    {
        float ba0 = 0.f, bc0 = 0.f, ba1 = 0.f, bc1 = 0.f;
        float da0 = 0.f, dc0 = 0.f, da1 = 0.f, dc1 = 0.f;
        #pragma unroll 4
        for (int i = 0; i < 16; ++i) {
            int   kj = pm[(seg << 4) + i];
            float w  = w1s[kj];
            float bb = b1s[kj];
            float2 v = *reinterpret_cast<const float2*>(&W2n[kj * 256 + d0]);
            if (w < 0.f) {
                ba0 = fmaf(v.x, w, ba0); bc0 = fmaf(v.x, bb, bc0);
                ba1 = fmaf(v.y, w, ba1); bc1 = fmaf(v.y, bb, bc1);
            }
            float aw = fabsf(w);
            float cs = (w > 0.f) ? bb : -bb;
            da0 = fmaf(v.x, aw, da0); dc0 = fmaf(v.x, cs, dc0);
            da1 = fmaf(v.y, aw, da1); dc1 = fmaf(v.y, cs, dc1);
        }
        float* p = part[seg][prl];
        p[0] = ba0; p[1] = bc0; p[2] = ba1; p[3] = bc1;
        p[4] = da0; p[5] = dc0; p[6] = da1; p[7] = dc1;
    }
    __syncthreads();

    // ---- phase 2: base totals + exclusive seg prefix (16 threads) ----
    if (tid < 16) {
        const int pr = tid;
        float sa0 = 0.f, sc0 = 0.f, sa1 = 0.f, sc1 = 0.f;
        #pragma unroll
        for (int sg = 0; sg < 16; ++sg) {
            const float* p = part[sg][pr];
            sa0 += p[0]; sc0 += p[1]; sa1 += p[2]; sc1 += p[3];
        }
        const int dd = ((strip << 4) + pr) << 1;
        sc0 += b2[n * 256 + dd];
        sc1 += b2[n * 256 + dd + 1];
        table[(size_t)n * 257 * 128 + ((strip << 4) + pr)] =
            make_uint2(pk2(sa0, sc0), pk2(sa1, sc1));
        float ra0 = sa0, rc0 = sc0, ra1 = sa1, rc1 = sc1;
        #pragma unroll
        for (int sg = 0; sg < 16; ++sg) {
            float* p = part[sg][pr];
            float t4 = p[4], t5 = p[5], t6 = p[6], t7 = p[7];
            p[0] = ra0; p[1] = rc0; p[2] = ra1; p[3] = rc1;
            ra0 += t4; rc0 += t5; ra1 += t6; rc1 += t7;
        }
    }
    __syncthreads();

    // ---- phase 3: re-walk segment from start, write 16 rows ----
    {
        const float* p = part[seg][prl];
        float a0 = p[0], c0 = p[1], a1 = p[2], c1 = p[3];
        uint2* trow = table + (size_t)n * 257 * 128 + prg;
        #pragma unroll 4
        for (int i = 0; i < 16; ++i) {
            int   j  = (seg << 4) + i;
            int   kj = pm[j];
            float w  = w1s[kj];
            float bb = b1s[kj];
            float2 v = *reinterpret_cast<const float2*>(&W2n[kj * 256 + d0]);
            float aw = fabsf(w);
            float cs = (w > 0.f) ? bb : -bb;
            a0 = fmaf(v.x, aw, a0); c0 = fmaf(v.x, cs, c0);
            a1 = fmaf(v.y, aw, a1); c1 = fmaf(v.y, cs, c1);
            trow[(size_t)(j + 1) * 128] = make_uint2(pk2(a0, c0), pk2(a1, c1));
        }
    }
}

// ---------------------------------------------------------------------------
// Kernel 3: evaluate z[n][b]. Block = (node, 256-sample chunk), 256 thr,
// 1 sample/thread. grid (64, 32) = 2048 blocks -> 32 waves/CU.
// Count-sort samples by interval so consecutive lanes share table rows.
// ---------------------------------------------------------------------------
__global__ __launch_bounds__(256) void eval_nodes(
    const float* __restrict__ S, const float* __restrict__ knots,
    const uint2* __restrict__ table, const float* __restrict__ W3,
    const float* __restrict__ b3, float* __restrict__ Z)
{
    __shared__ float kn[256];
    __shared__ float w3s[256];
    __shared__ float ssv[256];
    __shared__ u32   meta[256];
    __shared__ u32   hist[257];

    const int n   = blockIdx.x;
    const int c0  = blockIdx.y << 8;
    const int tid = threadIdx.x;
    const int lane = tid & 63;

    kn[tid]  = knots[n * 256 + tid];
    w3s[tid] = W3[n * 256 + tid];
    hist[tid] = 0;
    if (tid == 0) hist[256] = 0;

    const float sv = S[((size_t)n << 13) + c0 + tid];
    __syncthreads();

    // branchless lower_bound: I = #knots < sv, in [0,256]
    int I = 0;
    #pragma unroll
    for (int step = 128; step >= 1; step >>= 1)
        if (kn[I + step - 1] < sv) I += step;
    if (kn[I > 255 ? 255 : I] < sv && I < 256) I += 1;
    atomicAdd(&hist[I], 1u);
    __syncthreads();

    // wave-parallel exclusive prefix over hist[0..255]; hist[256] start ok
    if (tid < 64) {
        int base = tid << 2;
        u32 h0 = hist[base], h1 = hist[base + 1], h2 = hist[base + 2], h3 = hist[base + 3];
        u32 lsum = h0 + h1 + h2 + h3;
        u32 run = lsum;
        #pragma unroll
        for (int off = 1; off < 64; off <<= 1) {
            u32 tt = __shfl_up(run, off, 64);
            if (lane >= off) run += tt;
        }
        u32 excl = run - lsum;
        hist[base]     = excl;
        hist[base + 1] = excl + h0;
        hist[base + 2] = excl + h0 + h1;
        hist[base + 3] = excl + h0 + h1 + h2;
        if (tid == 63) hist[256] = excl + lsum;
    }
    __syncthreads();

    {
        u32 pos = atomicAdd(&hist[I], 1u);
        ssv[pos]  = sv;
        meta[pos] = ((u32)I << 8) | (u32)tid;
    }
    __syncthreads();

    const float b3n = b3[n];
    const float s   = ssv[tid];
    const u32   m   = meta[tid];
    const int   bl  = (int)(m & 255u);
    const uint4* row = reinterpret_cast<const uint4*>(
        table + (size_t)((u32)n * 257 + (m >> 8)) * 128);   // 64 x uint4

    float acc0 = 0.f, acc1 = 0.f;
    #pragma unroll 4
    for (int q = 0; q < 64; ++q) {
        uint4  v   = row[q];
        float4 w3q = *reinterpret_cast<const float4*>(&w3s[q << 2]);
        float h0 = fmaxf(fmaf(bfl(v.x), s, bfh(v.x)), 0.f);
        float h1 = fmaxf(fmaf(bfl(v.y), s, bfh(v.y)), 0.f);
        float h2 = fmaxf(fmaf(bfl(v.z), s, bfh(v.z)), 0.f);
        float h3 = fmaxf(fmaf(bfl(v.w), s, bfh(v.w)), 0.f);
        acc0 = fmaf(h0, w3q.x, fmaf(h1, w3q.y, acc0));
        acc1 = fmaf(h2, w3q.z, fmaf(h3, w3q.w, acc1));
    }
    Z[((size_t)n << 13) + c0 + bl] = acc0 + acc1 + b3n;
}

// ---------------------------------------------------------------------------
// Kernel 4: 65-way softmax, Z read via 64x64 LDS transpose (coalesced).
// Block = 64 batch rows; wave wv processes rows wv*16..wv*16+15.
// ---------------------------------------------------------------------------
__global__ __launch_bounds__(256) void softmax_rows(
    const float* __restrict__ Q, const float* __restrict__ Y,
    const float* __restrict__ Z, const float* __restrict__ bias0,
    float* __restrict__ out)
{
    __shared__ float ts[64][65];
    const int b0   = blockIdx.x << 6;
    const int tid  = threadIdx.x;
    const int lane = tid & 63;
    const int wv   = tid >> 6;

    #pragma unroll
    for (int jj = 0; jj < 16; jj++) {
        int idx = tid + (jj << 8);
        int nn = idx >> 6, bb = idx & 63;
        ts[bb][nn] = Z[((size_t)nn << 13) + b0 + bb];
    }
    __syncthreads();

    const float bias = bias0[0];
    #pragma unroll 2
    for (int r = 0; r < 16; ++r) {
        const int row = (wv << 4) + r;
        const int b   = b0 + row;

        float s = Q[(size_t)b * 64 + lane] * Y[(size_t)b * 64 + lane];
        float ssum = s;
        #pragma unroll
        for (int mask = 32; mask >= 1; mask >>= 1) ssum += __shfl_xor(ssum, mask, 64);
        const float z0 = bias - ssum;

        float zl = ts[row][lane];
        float mx = zl;
        #pragma unroll
        for (int mask = 32; mask >= 1; mask >>= 1) mx = fmaxf(mx, __shfl_xor(mx, mask, 64));
        mx = fmaxf(mx, z0);

        float el = expf(zl - mx);
        float e0 = expf(z0 - mx);
        float den = el;
        #pragma unroll
        for (int mask = 32; mask >= 1; mask >>= 1) den += __shfl_xor(den, mask, 64);
        den += e0;
        const float inv = 1.0f / den;

        out[(size_t)b * 65 + 1 + lane] = el * inv;
        if (lane == 0) out[(size_t)b * 65] = e0 * inv;
    }
}

// ---------------------------------------------------------------------------
extern "C" void kernel_launch(void* const* d_in, const int* in_sizes, int n_in,
                              void* d_out, int out_size, void* d_ws, size_t ws_size,
                              hipStream_t stream)
{
    const float* Q     = (const float*)d_in[0];
    const float* Y     = (const float*)d_in[1];
    const float* W1    = (const float*)d_in[2];
    const float* b1    = (const float*)d_in[3];
    const float* W2    = (const float*)d_in[4];
    const float* b2    = (const float*)d_in[5];
    const float* W3    = (const float*)d_in[6];
    const float* b3    = (const float*)d_in[7];
    const float* bias0 = (const float*)d_in[8];
    float* out = (float*)d_out;

    // ws layout (bytes):
    // [0        ) table  64*257*128*8 = 16,842,752
    // [16842752 ) S      2,097,152
    // [18939904 ) Z      2,097,152
    // [21037056 ) knots  65,536
    // [21102592 ) perm   65,536     total 21,168,128
    char* ws = (char*)d_ws;
    uint2* table = (uint2*)ws;
    float* S     = (float*)(ws + 16842752);
    float* Z     = (float*)(ws + 18939904);
    float* knots = (float*)(ws + 21037056);
    int*   perm  = (int*)  (ws + 21102592);

    make_s<<<128, 256, 0, stream>>>(Q, Y, S);
    knee_sort<<<64, 256, 0, stream>>>(W1, b1, knots, perm);
    scan_build<<<dim3(64, 8), 256, 0, stream>>>(W1, b1, W2, b2, perm, table);
    eval_nodes<<<dim3(64, 32), 256, 0, stream>>>(S, knots, table, W3, b3, Z);
    softmax_rows<<<128, 256, 0, stream>>>(Q, Y, Z, bias0, out);
}

// Round 14
// 74.120 us; speedup vs baseline: 1.8647x; 1.0930x over previous
//
#include <hip/hip_runtime.h>
#include <hip/hip_bf16.h>

// B=8192 rows, N=64 nodes, C=256. Per node: MLP 1->C->C->1 on s=Q*Y, then
// softmax over [z0, z_1..z_64]. Output f32 [B, 65].
//
// Round 14: piecewise-linear path; GLOBAL per-node sample sort + f16 table.
//  - sort_nodes: per node, bucket all 8192 samples by interval -> sorted[]
//    (eval waves then span ~2 intervals -> table loads broadcast, L2-light)
//  - table entries f16 alpha-pair/beta-pair: eval inner = pk_fma + pk_max +
//    v_dot2_f32_f16 (one asm opcode; pk ops via clang vector types)

typedef unsigned int u32;
typedef __fp16 fp16x2 __attribute__((ext_vector_type(2)));
union U32H { u32 u; fp16x2 h; };

__device__ __forceinline__ u32 pkh(float a, float b) {   // lo=f16(a), hi=f16(b)
    U32H cv; cv.h = __builtin_amdgcn_cvt_pkrtz(a, b); return cv.u;
}
__device__ __forceinline__ float dot2f(u32 a, u32 b, float c) {
    float d;
    asm("v_dot2_f32_f16 %0, %1, %2, %3" : "=v"(d) : "v"(a), "v"(b), "v"(c));
    return d;
}

// ---------------------------------------------------------------------------
// Kernel 0: S[n][b] = Q[b][n]*Y[b][n]  (node-major, 64x64 LDS transpose)
// ---------------------------------------------------------------------------
__global__ __launch_bounds__(256) void make_s(
    const float* __restrict__ Q, const float* __restrict__ Y,
    float* __restrict__ S)
{
    __shared__ float ts[64][65];
    const int b0 = blockIdx.x << 6;
    #pragma unroll
    for (int jj = 0; jj < 16; jj++) {
        int idx = threadIdx.x + (jj << 8);
        int r = idx >> 6, c = idx & 63;
        ts[r][c] = Q[(size_t)(b0 + r) * 64 + c] * Y[(size_t)(b0 + r) * 64 + c];
    }
    __syncthreads();
    #pragma unroll
    for (int jj = 0; jj < 16; jj++) {
        int idx = threadIdx.x + (jj << 8);
        int nn = idx >> 6, bb = idx & 63;
        S[((size_t)nn << 13) + b0 + bb] = ts[bb][nn];
    }
}

// ---------------------------------------------------------------------------
// Kernel 1: per node, knees s*_k = -b1_k/w1_k, bitonic sort (key + index).
// ---------------------------------------------------------------------------
__global__ __launch_bounds__(256) void knee_sort(
    const float* __restrict__ W1, const float* __restrict__ b1,
    float* __restrict__ knots, int* __restrict__ perm)
{
    __shared__ float key[256];
    __shared__ int   idx[256];
    const int n = blockIdx.x;
    const int t = threadIdx.x;
    {
        float w = W1[n * 256 + t];
        float b = b1[n * 256 + t];
        key[t] = -b / w;                 // +-inf when w ~ 0: sorts to the ends
        idx[t] = t;
    }
    __syncthreads();
    for (int k = 2; k <= 256; k <<= 1) {
        for (int j = k >> 1; j > 0; j >>= 1) {
            int p = t ^ j;
            if (p > t) {
                float a = key[t], c = key[p];
                bool up = ((t & k) == 0);
                if (up ? (a > c) : (a < c)) {
                    int ia = idx[t];
                    key[t] = c; idx[t] = idx[p];
                    key[p] = a; idx[p] = ia;
                }
            }
            __syncthreads();
        }
    }
    knots[n * 256 + t] = key[t];
    perm[n * 256 + t]  = idx[t];
}

// ---------------------------------------------------------------------------
// Kernel 2: segmented-scan build of the f16 interval table.
// table[(n*257+I)*128+pr] = uint2{ f16x2(alpha_d0, alpha_d1),
//                                  f16x2(beta_d0,  beta_d1) }.
// grid (64 nodes, 8 d-strips of 32), 256 thr = (seg 0..15) x (pair 0..15).
// ---------------------------------------------------------------------------
__global__ __launch_bounds__(256) void scan_build(
    const float* __restrict__ W1, const float* __restrict__ b1,
    const float* __restrict__ W2, const float* __restrict__ b2,
    const int* __restrict__ perm, uint2* __restrict__ table)
{
    __shared__ float w1s[256], b1s[256];
    __shared__ int   pm[256];
    __shared__ float part[16][16][8];

    const int n    = blockIdx.x;
    const int strip= blockIdx.y;
    const int tid  = threadIdx.x;
    const int prl  = tid & 15;
    const int seg  = tid >> 4;
    const int prg  = (strip << 4) + prl;
    const int d0   = prg << 1;

    w1s[tid] = W1[n * 256 + tid];
    b1s[tid] = b1[n * 256 + tid];
    pm[tid]  = perm[n * 256 + tid];
    __syncthreads();

    const float* W2n = W2 + ((size_t)n << 16);

    // ---- phase 1: per-segment partials ----
    {
        float ba0 = 0.f, bc0 = 0.f, ba1 = 0.f, bc1 = 0.f;
        float da0 = 0.f, dc0 = 0.f, da1 = 0.f, dc1 = 0.f;
        #pragma unroll 4
        for (int i = 0; i < 16; ++i) {
            int   kj = pm[(seg << 4) + i];
            float w  = w1s[kj];
            float bb = b1s[kj];
            float2 v = *reinterpret_cast<const float2*>(&W2n[kj * 256 + d0]);
            if (w < 0.f) {
                ba0 = fmaf(v.x, w, ba0); bc0 = fmaf(v.x, bb, bc0);
                ba1 = fmaf(v.y, w, ba1); bc1 = fmaf(v.y, bb, bc1);
            }
            float aw = fabsf(w);
            float cs = (w > 0.f) ? bb : -bb;
            da0 = fmaf(v.x, aw, da0); dc0 = fmaf(v.x, cs, dc0);
            da1 = fmaf(v.y, aw, da1); dc1 = fmaf(v.y, cs, dc1);
        }
        float* p = part[seg][prl];
        p[0] = ba0; p[1] = bc0; p[2] = ba1; p[3] = bc1;
        p[4] = da0; p[5] = dc0; p[6] = da1; p[7] = dc1;
    }
    __syncthreads();

    // ---- phase 2: base totals + exclusive seg prefix (16 threads) ----
    if (tid < 16) {
        const int pr = tid;
        float sa0 = 0.f, sc0 = 0.f, sa1 = 0.f, sc1 = 0.f;
        #pragma unroll
        for (int sg = 0; sg < 16; ++sg) {
            const float* p = part[sg][pr];
            sa0 += p[0]; sc0 += p[1]; sa1 += p[2]; sc1 += p[3];
        }
        const int dd = ((strip << 4) + pr) << 1;
        sc0 += b2[n * 256 + dd];
        sc1 += b2[n * 256 + dd + 1];
        table[(size_t)n * 257 * 128 + ((strip << 4) + pr)] =
            make_uint2(pkh(sa0, sa1), pkh(sc0, sc1));
        float ra0 = sa0, rc0 = sc0, ra1 = sa1, rc1 = sc1;
        #pragma unroll
        for (int sg = 0; sg < 16; ++sg) {
            float* p = part[sg][pr];
            float t4 = p[4], t5 = p[5], t6 = p[6], t7 = p[7];
            p[0] = ra0; p[1] = rc0; p[2] = ra1; p[3] = rc1;
            ra0 += t4; rc0 += t5; ra1 += t6; rc1 += t7;
        }
    }
    __syncthreads();

    // ---- phase 3: re-walk segment from start, write 16 rows ----
    {
        const float* p = part[seg][prl];
        float a0 = p[0], c0 = p[1], a1 = p[2], c1 = p[3];
        uint2* trow = table + (size_t)n * 257 * 128 + prg;
        #pragma unroll 4
        for (int i = 0; i < 16; ++i) {
            int   j  = (seg << 4) + i;
            int   kj = pm[j];
            float w  = w1s[kj];
            float bb = b1s[kj];
            float2 v = *reinterpret_cast<const float2*>(&W2n[kj * 256 + d0]);
            float aw = fabsf(w);
            float cs = (w > 0.f) ? bb : -bb;
            a0 = fmaf(v.x, aw, a0); c0 = fmaf(v.x, cs, c0);
            a1 = fmaf(v.y, aw, a1); c1 = fmaf(v.y, cs, c1);
            trow[(size_t)(j + 1) * 128] = make_uint2(pkh(a0, a1), pkh(c0, c1));
        }
    }
}

// ---------------------------------------------------------------------------
// Kernel 3: global per-node sample sort by interval.
// One block per node, 1024 threads x 8 samples. sorted[n*8192+pos] =
// uint2{ bits(s), (I<<13) | b }.
// ---------------------------------------------------------------------------
__global__ __launch_bounds__(1024) void sort_nodes(
    const float* __restrict__ S, const float* __restrict__ knots,
    uint2* __restrict__ sorted)
{
    __shared__ float kn[256];
    __shared__ u32   hist[257];

    const int n   = blockIdx.x;
    const int tid = threadIdx.x;
    const int lane = tid & 63;

    if (tid < 256) kn[tid] = knots[n * 256 + tid];
    if (tid < 257) hist[tid] = 0;
    __syncthreads();

    const float* Sn = S + ((size_t)n << 13);
    float sv[8]; int iv[8];
    #pragma unroll
    for (int j = 0; j < 8; ++j) {
        const float s = Sn[tid + (j << 10)];
        sv[j] = s;
        int I = 0;
        #pragma unroll
        for (int step = 128; step >= 1; step >>= 1)
            if (kn[I + step - 1] < s) I += step;
        if (I < 256 && kn[I] < s) I += 1;
        iv[j] = I;
        atomicAdd(&hist[I], 1u);
    }
    __syncthreads();

    // wave 0: exclusive prefix over hist[0..255], hist[256] = total of 0..255
    if (tid < 64) {
        int base = tid << 2;
        u32 h0 = hist[base], h1 = hist[base + 1], h2 = hist[base + 2], h3 = hist[base + 3];
        u32 lsum = h0 + h1 + h2 + h3;
        u32 run = lsum;
        #pragma unroll
        for (int off = 1; off < 64; off <<= 1) {
            u32 tt = __shfl_up(run, off, 64);
            if (lane >= off) run += tt;
        }
        u32 excl = run - lsum;
        hist[base]     = excl;
        hist[base + 1] = excl + h0;
        hist[base + 2] = excl + h0 + h1;
        hist[base + 3] = excl + h0 + h1 + h2;
        if (tid == 63) hist[256] = excl + lsum;
    }
    __syncthreads();

    uint2* dst = sorted + ((size_t)n << 13);
    #pragma unroll
    for (int j = 0; j < 8; ++j) {
        u32 pos = atomicAdd(&hist[iv[j]], 1u);
        dst[pos] = make_uint2(__float_as_uint(sv[j]),
                              ((u32)iv[j] << 13) | (u32)(tid + (j << 10)));
    }
}

// ---------------------------------------------------------------------------
// Kernel 4: evaluate z. Block = 256 consecutive SORTED samples of one node.
// grid (64, 32). Inner: 64 x uint4 x {pk_fma, pk_max, dot2} in f16.
// ---------------------------------------------------------------------------
__global__ __launch_bounds__(256) void eval_nodes(
    const uint2* __restrict__ sorted, const uint2* __restrict__ table,
    const float* __restrict__ W3, const float* __restrict__ b3,
    float* __restrict__ Z)
{
    __shared__ u32 w3p[128];

    const int n   = blockIdx.x;
    const int c0  = blockIdx.y << 8;
    const int tid = threadIdx.x;

    if (tid < 128)
        w3p[tid] = pkh(W3[n * 256 + (tid << 1)], W3[n * 256 + (tid << 1) + 1]);
    __syncthreads();

    const uint2 ent = sorted[((size_t)n << 13) + c0 + tid];
    const float s   = __uint_as_float(ent.x);
    const int   I   = (int)(ent.y >> 13);
    const int   bl  = (int)(ent.y & 8191u);

    U32H s2; s2.u = pkh(s, s);
    const fp16x2 z2 = (fp16x2)0;

    const uint4* row = reinterpret_cast<const uint4*>(
        table + (size_t)((u32)n * 257 + I) * 128);   // 64 x uint4 = 4 d each

    float acc0 = 0.f, acc1 = 0.f;
    #pragma unroll 4
    for (int q = 0; q < 64; ++q) {
        uint4 v = row[q];
        uint2 w = reinterpret_cast<const uint2*>(w3p)[q];
        U32H a01{v.x}, b01{v.y}, a23{v.z}, b23{v.w};
        U32H h01, h23;
        h01.h = __builtin_elementwise_max(a01.h * s2.h + b01.h, z2);
        h23.h = __builtin_elementwise_max(a23.h * s2.h + b23.h, z2);
        acc0 = dot2f(h01.u, w.x, acc0);
        acc1 = dot2f(h23.u, w.y, acc1);
    }
    Z[((size_t)n << 13) + bl] = acc0 + acc1 + b3[n];
}

// ---------------------------------------------------------------------------
// Kernel 5: 65-way softmax, Z read via 64x64 LDS transpose (coalesced).
// ---------------------------------------------------------------------------
__global__ __launch_bounds__(256) void softmax_rows(
    const float* __restrict__ Q, const float* __restrict__ Y,
    const float* __restrict__ Z, const float* __restrict__ bias0,
    float* __restrict__ out)
{
    __shared__ float ts[64][65];
    const int b0   = blockIdx.x << 6;
    const int tid  = threadIdx.x;
    const int lane = tid & 63;
    const int wv   = tid >> 6;

    #pragma unroll
    for (int jj = 0; jj < 16; jj++) {
        int idx = tid + (jj << 8);
        int nn = idx >> 6, bb = idx & 63;
        ts[bb][nn] = Z[((size_t)nn << 13) + b0 + bb];
    }
    __syncthreads();

    const float bias = bias0[0];
    #pragma unroll 2
    for (int r = 0; r < 16; ++r) {
        const int row = (wv << 4) + r;
        const int b   = b0 + row;

        float s = Q[(size_t)b * 64 + lane] * Y[(size_t)b * 64 + lane];
        float ssum = s;
        #pragma unroll
        for (int mask = 32; mask >= 1; mask >>= 1) ssum += __shfl_xor(ssum, mask, 64);
        const float z0 = bias - ssum;

        float zl = ts[row][lane];
        float mx = zl;
        #pragma unroll
        for (int mask = 32; mask >= 1; mask >>= 1) mx = fmaxf(mx, __shfl_xor(mx, mask, 64));
        mx = fmaxf(mx, z0);

        float el = expf(zl - mx);
        float e0 = expf(z0 - mx);
        float den = el;
        #pragma unroll
        for (int mask = 32; mask >= 1; mask >>= 1) den += __shfl_xor(den, mask, 64);
        den += e0;
        const float inv = 1.0f / den;

        out[(size_t)b * 65 + 1 + lane] = el * inv;
        if (lane == 0) out[(size_t)b * 65] = e0 * inv;
    }
}

// ---------------------------------------------------------------------------
extern "C" void kernel_launch(void* const* d_in, const int* in_sizes, int n_in,
                              void* d_out, int out_size, void* d_ws, size_t ws_size,
                              hipStream_t stream)
{
    const float* Q     = (const float*)d_in[0];
    const float* Y     = (const float*)d_in[1];
    const float* W1    = (const float*)d_in[2];
    const float* b1    = (const float*)d_in[3];
    const float* W2    = (const float*)d_in[4];
    const float* b2    = (const float*)d_in[5];
    const float* W3    = (const float*)d_in[6];
    const float* b3    = (const float*)d_in[7];
    const float* bias0 = (const float*)d_in[8];
    float* out = (float*)d_out;

    // ws layout (bytes):
    // [0        ) table   64*257*128*8 = 16,842,752
    // [16842752 ) S       2,097,152
    // [18939904 ) Z       2,097,152
    // [21037056 ) knots   65,536
    // [21102592 ) perm    65,536
    // [21168128 ) sorted  64*8192*8 = 4,194,304    total 25,362,432
    char* ws = (char*)d_ws;
    uint2* table  = (uint2*)ws;
    float* S      = (float*)(ws + 16842752);
    float* Z      = (float*)(ws + 18939904);
    float* knots  = (float*)(ws + 21037056);
    int*   perm   = (int*)  (ws + 21102592);
    uint2* sorted = (uint2*)(ws + 21168128);

    make_s<<<128, 256, 0, stream>>>(Q, Y, S);
    knee_sort<<<64, 256, 0, stream>>>(W1, b1, knots, perm);
    scan_build<<<dim3(64, 8), 256, 0, stream>>>(W1, b1, W2, b2, perm, table);
    sort_nodes<<<64, 1024, 0, stream>>>(S, knots, sorted);
    eval_nodes<<<dim3(64, 32), 256, 0, stream>>>(sorted, table, W3, b3, Z);
    softmax_rows<<<128, 256, 0, stream>>>(Q, Y, Z, bias0, out);
}

// Round 15
// 63.608 us; speedup vs baseline: 2.1728x; 1.1653x over previous
//
#include <hip/hip_runtime.h>
#include <hip/hip_bf16.h>

// B=8192 rows, N=64 nodes, C=256. Per node: MLP 1->C->C->1 on s=Q*Y, then
// softmax over [z0, z_1..z_64]. Output f32 [B, 65].
//
// Round 15: piecewise-linear path; launch-fusion + sort occupancy.
//  K1 prep       : blocks 0..127 make_s tiles, 128..191 knee_sort nodes
//  K2 build_sort : blocks 0..511 scan_build (n,strip), 512..767 sort quarters
//                  (256 blocks of (node, 2048-sample quarter) -> 4x occupancy)
//  K3 eval_nodes : unchanged f16 table eval (sorted samples)
//  K4 softmax    : unchanged

typedef unsigned int u32;
typedef __fp16 fp16x2 __attribute__((ext_vector_type(2)));
union U32H { u32 u; fp16x2 h; };

__device__ __forceinline__ u32 pkh(float a, float b) {   // lo=f16(a), hi=f16(b)
    U32H cv; cv.h = __builtin_amdgcn_cvt_pkrtz(a, b); return cv.u;
}
__device__ __forceinline__ float dot2f(u32 a, u32 b, float c) {
    float d;
    asm("v_dot2_f32_f16 %0, %1, %2, %3" : "=v"(d) : "v"(a), "v"(b), "v"(c));
    return d;
}

// ---------------------------------------------------------------------------
// K1: prep. blocks 0..127: S[n][b] = Q[b][n]*Y[b][n] (64x64 LDS transpose).
//           blocks 128..191: knee s*_k = -b1_k/w1_k + bitonic sort.
// ---------------------------------------------------------------------------
__global__ __launch_bounds__(256) void prep(
    const float* __restrict__ Q, const float* __restrict__ Y,
    const float* __restrict__ W1, const float* __restrict__ b1,
    float* __restrict__ S, float* __restrict__ knots, int* __restrict__ perm)
{
    __shared__ float ts[64][65];
    __shared__ float key[256];
    __shared__ int   idx[256];

    const int blk = blockIdx.x;
    const int tid = threadIdx.x;

    if (blk < 128) {
        const int b0 = blk << 6;
        #pragma unroll
        for (int jj = 0; jj < 16; jj++) {
            int i = tid + (jj << 8);
            int r = i >> 6, c = i & 63;
            ts[r][c] = Q[(size_t)(b0 + r) * 64 + c] * Y[(size_t)(b0 + r) * 64 + c];
        }
        __syncthreads();
        #pragma unroll
        for (int jj = 0; jj < 16; jj++) {
            int i = tid + (jj << 8);
            int nn = i >> 6, bb = i & 63;
            S[((size_t)nn << 13) + b0 + bb] = ts[bb][nn];
        }
    } else {
        const int n = blk - 128;
        {
            float w = W1[n * 256 + tid];
            float b = b1[n * 256 + tid];
            key[tid] = -b / w;           // +-inf when w ~ 0: sorts to the ends
            idx[tid] = tid;
        }
        __syncthreads();
        for (int k = 2; k <= 256; k <<= 1) {
            for (int j = k >> 1; j > 0; j >>= 1) {
                int p = tid ^ j;
                if (p > tid) {
                    float a = key[tid], c = key[p];
                    bool up = ((tid & k) == 0);
                    if (up ? (a > c) : (a < c)) {
                        int ia = idx[tid];
                        key[tid] = c; idx[tid] = idx[p];
                        key[p] = a; idx[p] = ia;
                    }
                }
                __syncthreads();
            }
        }
        knots[n * 256 + tid] = key[tid];
        perm[n * 256 + tid]  = idx[tid];
    }
}

// ---------------------------------------------------------------------------
// K2: build_sort.
// blocks 0..511: segmented-scan table build; (n = blk>>3, strip = blk&7),
//   256 thr = (seg 0..15) x (pair 0..15).
//   table[(n*257+I)*128+pr] = uint2{ f16x2(a_d0,a_d1), f16x2(b_d0,b_d1) }.
// blocks 512..767: sort one (node, quarter): 2048 samples bucketed by
//   interval -> sorted[n*8192 + q*2048 + pos] = { bits(s), (I<<13)|b }.
// ---------------------------------------------------------------------------
__global__ __launch_bounds__(256) void build_sort(
    const float* __restrict__ W1, const float* __restrict__ b1,
    const float* __restrict__ W2, const float* __restrict__ b2,
    const int* __restrict__ perm, const float* __restrict__ S,
    const float* __restrict__ knots,
    uint2* __restrict__ table, uint2* __restrict__ sorted)
{
    __shared__ float w1s[256], b1s[256];
    __shared__ int   pm[256];
    __shared__ float part[16][16][8];
    __shared__ u32   hist[257];

    const int blk = blockIdx.x;
    const int tid = threadIdx.x;
    const int lane = tid & 63;

    if (blk < 512) {
        // ================= scan_build role =================
        const int n    = blk >> 3;
        const int strip= blk & 7;
        const int prl  = tid & 15;
        const int seg  = tid >> 4;
        const int prg  = (strip << 4) + prl;
        const int d0   = prg << 1;

        w1s[tid] = W1[n * 256 + tid];
        b1s[tid] = b1[n * 256 + tid];
        pm[tid]  = perm[n * 256 + tid];
        __syncthreads();

        const float* W2n = W2 + ((size_t)n << 16);

        // phase 1: per-segment partials
        {
            float ba0 = 0.f, bc0 = 0.f, ba1 = 0.f, bc1 = 0.f;
            float da0 = 0.f, dc0 = 0.f, da1 = 0.f, dc1 = 0.f;
            #pragma unroll 4
            for (int i = 0; i < 16; ++i) {
                int   kj = pm[(seg << 4) + i];
                float w  = w1s[kj];
                float bb = b1s[kj];
                float2 v = *reinterpret_cast<const float2*>(&W2n[kj * 256 + d0]);
                if (w < 0.f) {
                    ba0 = fmaf(v.x, w, ba0); bc0 = fmaf(v.x, bb, bc0);
                    ba1 = fmaf(v.y, w, ba1); bc1 = fmaf(v.y, bb, bc1);
                }
                float aw = fabsf(w);
                float cs = (w > 0.f) ? bb : -bb;
                da0 = fmaf(v.x, aw, da0); dc0 = fmaf(v.x, cs, dc0);
                da1 = fmaf(v.y, aw, da1); dc1 = fmaf(v.y, cs, dc1);
            }
            float* p = part[seg][prl];
            p[0] = ba0; p[1] = bc0; p[2] = ba1; p[3] = bc1;
            p[4] = da0; p[5] = dc0; p[6] = da1; p[7] = dc1;
        }
        __syncthreads();

        // phase 2: base totals + exclusive seg prefix (16 threads)
        if (tid < 16) {
            const int pr = tid;
            float sa0 = 0.f, sc0 = 0.f, sa1 = 0.f, sc1 = 0.f;
            #pragma unroll
            for (int sg = 0; sg < 16; ++sg) {
                const float* p = part[sg][pr];
                sa0 += p[0]; sc0 += p[1]; sa1 += p[2]; sc1 += p[3];
            }
            const int dd = ((strip << 4) + pr) << 1;
            sc0 += b2[n * 256 + dd];
            sc1 += b2[n * 256 + dd + 1];
            table[(size_t)n * 257 * 128 + ((strip << 4) + pr)] =
                make_uint2(pkh(sa0, sa1), pkh(sc0, sc1));
            float ra0 = sa0, rc0 = sc0, ra1 = sa1, rc1 = sc1;
            #pragma unroll
            for (int sg = 0; sg < 16; ++sg) {
                float* p = part[sg][pr];
                float t4 = p[4], t5 = p[5], t6 = p[6], t7 = p[7];
                p[0] = ra0; p[1] = rc0; p[2] = ra1; p[3] = rc1;
                ra0 += t4; rc0 += t5; ra1 += t6; rc1 += t7;
            }
        }
        __syncthreads();

        // phase 3: re-walk segment, write 16 rows
        {
            const float* p = part[seg][prl];
            float a0 = p[0], c0 = p[1], a1 = p[2], c1 = p[3];
            uint2* trow = table + (size_t)n * 257 * 128 + prg;
            #pragma unroll 4
            for (int i = 0; i < 16; ++i) {
                int   j  = (seg << 4) + i;
                int   kj = pm[j];
                float w  = w1s[kj];
                float bb = b1s[kj];
                float2 v = *reinterpret_cast<const float2*>(&W2n[kj * 256 + d0]);
                float aw = fabsf(w);
                float cs = (w > 0.f) ? bb : -bb;
                a0 = fmaf(v.x, aw, a0); c0 = fmaf(v.x, cs, c0);
                a1 = fmaf(v.y, aw, a1); c1 = fmaf(v.y, cs, c1);
                trow[(size_t)(j + 1) * 128] = make_uint2(pkh(a0, a1), pkh(c0, c1));
            }
        }
    } else {
        // ================= sort role: (node, quarter) =================
        const int t = blk - 512;
        const int n = t >> 2;
        const int q = t & 3;

        // reuse w1s[] LDS as the knot table
        float* kn = w1s;
        kn[tid] = knots[n * 256 + tid];
        hist[tid] = 0;
        if (tid == 0) hist[256] = 0;
        __syncthreads();

        const float* Sn = S + ((size_t)n << 13) + (q << 11);
        float sv[8]; int iv[8];
        #pragma unroll
        for (int j = 0; j < 8; ++j) {
            const float s = Sn[tid + (j << 8)];
            sv[j] = s;
            int I = 0;
            #pragma unroll
            for (int step = 128; step >= 1; step >>= 1)
                if (kn[I + step - 1] < s) I += step;
            if (I < 256 && kn[I] < s) I += 1;
            iv[j] = I;
            atomicAdd(&hist[I], 1u);
        }
        __syncthreads();

        if (tid < 64) {
            int base = tid << 2;
            u32 h0 = hist[base], h1 = hist[base + 1], h2 = hist[base + 2], h3 = hist[base + 3];
            u32 lsum = h0 + h1 + h2 + h3;
            u32 run = lsum;
            #pragma unroll
            for (int off = 1; off < 64; off <<= 1) {
                u32 tt = __shfl_up(run, off, 64);
                if (lane >= off) run += tt;
            }
            u32 excl = run - lsum;
            hist[base]     = excl;
            hist[base + 1] = excl + h0;
            hist[base + 2] = excl + h0 + h1;
            hist[base + 3] = excl + h0 + h1 + h2;
            if (tid == 63) hist[256] = excl + lsum;
        }
        __syncthreads();

        uint2* dst = sorted + ((size_t)n << 13) + (q << 11);
        #pragma unroll
        for (int j = 0; j < 8; ++j) {
            u32 pos = atomicAdd(&hist[iv[j]], 1u);
            u32 bglob = (u32)((q << 11) + tid + (j << 8));
            dst[pos] = make_uint2(__float_as_uint(sv[j]), ((u32)iv[j] << 13) | bglob);
        }
    }
}

// ---------------------------------------------------------------------------
// K3: evaluate z. Block = 256 consecutive SORTED samples of one node.
// grid (64, 32). Inner: 64 x uint4 x {pk_fma, pk_max, dot2} in f16.
// ---------------------------------------------------------------------------
__global__ __launch_bounds__(256) void eval_nodes(
    const uint2* __restrict__ sorted, const uint2* __restrict__ table,
    const float* __restrict__ W3, const float* __restrict__ b3,
    float* __restrict__ Z)
{
    __shared__ u32 w3p[128];

    const int n   = blockIdx.x;
    const int c0  = blockIdx.y << 8;
    const int tid = threadIdx.x;

    if (tid < 128)
        w3p[tid] = pkh(W3[n * 256 + (tid << 1)], W3[n * 256 + (tid << 1) + 1]);
    __syncthreads();

    const uint2 ent = sorted[((size_t)n << 13) + c0 + tid];
    const float s   = __uint_as_float(ent.x);
    const int   I   = (int)(ent.y >> 13);
    const int   bl  = (int)(ent.y & 8191u);

    U32H s2; s2.u = pkh(s, s);
    const fp16x2 z2 = (fp16x2)0;

    const uint4* row = reinterpret_cast<const uint4*>(
        table + (size_t)((u32)n * 257 + I) * 128);   // 64 x uint4 = 4 d each

    float acc0 = 0.f, acc1 = 0.f;
    #pragma unroll 4
    for (int q = 0; q < 64; ++q) {
        uint4 v = row[q];
        uint2 w = reinterpret_cast<const uint2*>(w3p)[q];
        U32H a01{v.x}, b01{v.y}, a23{v.z}, b23{v.w};
        U32H h01, h23;
        h01.h = __builtin_elementwise_max(a01.h * s2.h + b01.h, z2);
        h23.h = __builtin_elementwise_max(a23.h * s2.h + b23.h, z2);
        acc0 = dot2f(h01.u, w.x, acc0);
        acc1 = dot2f(h23.u, w.y, acc1);
    }
    Z[((size_t)n << 13) + bl] = acc0 + acc1 + b3[n];
}

// ---------------------------------------------------------------------------
// K4: 65-way softmax, Z read via 64x64 LDS transpose (coalesced).
// ---------------------------------------------------------------------------
__global__ __launch_bounds__(256) void softmax_rows(
    const float* __restrict__ Q, const float* __restrict__ Y,
    const float* __restrict__ Z, const float* __restrict__ bias0,
    float* __restrict__ out)
{
    __shared__ float ts[64][65];
    const int b0   = blockIdx.x << 6;
    const int tid  = threadIdx.x;
    const int lane = tid & 63;
    const int wv   = tid >> 6;

    #pragma unroll
    for (int jj = 0; jj < 16; jj++) {
        int idx = tid + (jj << 8);
        int nn = idx >> 6, bb = idx & 63;
        ts[bb][nn] = Z[((size_t)nn << 13) + b0 + bb];
    }
    __syncthreads();

    const float bias = bias0[0];
    #pragma unroll 2
    for (int r = 0; r < 16; ++r) {
        const int row = (wv << 4) + r;
        const int b   = b0 + row;

        float s = Q[(size_t)b * 64 + lane] * Y[(size_t)b * 64 + lane];
        float ssum = s;
        #pragma unroll
        for (int mask = 32; mask >= 1; mask >>= 1) ssum += __shfl_xor(ssum, mask, 64);
        const float z0 = bias - ssum;

        float zl = ts[row][lane];
        float mx = zl;
        #pragma unroll
        for (int mask = 32; mask >= 1; mask >>= 1) mx = fmaxf(mx, __shfl_xor(mx, mask, 64));
        mx = fmaxf(mx, z0);

        float el = expf(zl - mx);
        float e0 = expf(z0 - mx);
        float den = el;
        #pragma unroll
        for (int mask = 32; mask >= 1; mask >>= 1) den += __shfl_xor(den, mask, 64);
        den += e0;
        const float inv = 1.0f / den;

        out[(size_t)b * 65 + 1 + lane] = el * inv;
        if (lane == 0) out[(size_t)b * 65] = e0 * inv;
    }
}

// ---------------------------------------------------------------------------
extern "C" void kernel_launch(void* const* d_in, const int* in_sizes, int n_in,
                              void* d_out, int out_size, void* d_ws, size_t ws_size,
                              hipStream_t stream)
{
    const float* Q     = (const float*)d_in[0];
    const float* Y     = (const float*)d_in[1];
    const float* W1    = (const float*)d_in[2];
    const float* b1    = (const float*)d_in[3];
    const float* W2    = (const float*)d_in[4];
    const float* b2    = (const float*)d_in[5];
    const float* W3    = (const float*)d_in[6];
    const float* b3    = (const float*)d_in[7];
    const float* bias0 = (const float*)d_in[8];
    float* out = (float*)d_out;

    // ws layout (bytes):
    // [0        ) table   64*257*128*8 = 16,842,752
    // [16842752 ) S       2,097,152
    // [18939904 ) Z       2,097,152
    // [21037056 ) knots   65,536
    // [21102592 ) perm    65,536
    // [21168128 ) sorted  64*8192*8 = 4,194,304    total 25,362,432
    char* ws = (char*)d_ws;
    uint2* table  = (uint2*)ws;
    float* S      = (float*)(ws + 16842752);
    float* Z      = (float*)(ws + 18939904);
    float* knots  = (float*)(ws + 21037056);
    int*   perm   = (int*)  (ws + 21102592);
    uint2* sorted = (uint2*)(ws + 21168128);

    prep<<<192, 256, 0, stream>>>(Q, Y, W1, b1, S, knots, perm);
    build_sort<<<768, 256, 0, stream>>>(W1, b1, W2, b2, perm, S, knots, table, sorted);
    eval_nodes<<<dim3(64, 32), 256, 0, stream>>>(sorted, table, W3, b3, Z);
    softmax_rows<<<128, 256, 0, stream>>>(Q, Y, Z, bias0, out);
}